// Round 5
// baseline (3928.328 us; speedup 1.0000x reference)
//
#include <hip/hip_runtime.h>
#include <hip/hip_bf16.h>

#define L_ 8
#define B_ 8
#define T_ 1024
#define C_ 768
#define H_ 12
#define D_HEAD 64
#define V_ 1024
#define FF_ 3072
#define M_ (B_ * T_)  // 8192 rows

typedef __bf16 bf16x8 __attribute__((ext_vector_type(8)));
typedef float f32x4 __attribute__((ext_vector_type(4)));

typedef const __attribute__((address_space(1))) void* as1cvp;
typedef __attribute__((address_space(3))) void* as3vp;

__device__ __forceinline__ void async16(const void* g, void* l) {
  __builtin_amdgcn_global_load_lds((as1cvp)g, (as3vp)l, 16, 0, 0);
}

__device__ __forceinline__ float bf2f(unsigned short u) {
  union { unsigned u32; float f; } c; c.u32 = ((unsigned)u) << 16; return c.f;
}

__device__ __forceinline__ unsigned short f2bf(float f) {
  __hip_bfloat16 h = __float2bfloat16(f);
  return *(unsigned short*)&h;
}

// tanh-form GELU: x * sigmoid(2*0.7978845608*(x + 0.044715 x^3)).
// Max |err| vs erf-GELU ~1e-3; negligible after bf16 store + W2 contraction.
__device__ __forceinline__ float gelu_f(float x) {
  float u2 = x * (1.5957691216f + 0.0713548162f * x * x);
  return x / (1.f + __expf(-u2));
}

// ---------------------------------------------------------------------------
// Embedding: h[row, c] = embed[x[row]][c] + pos[row % T][c]; also bf16 copy.
// ---------------------------------------------------------------------------
__global__ __launch_bounds__(256) void embed_kernel(
    const int* __restrict__ x, const float* __restrict__ emb,
    const float* __restrict__ pos, float* __restrict__ h,
    __hip_bfloat16* __restrict__ hb) {
  int row = blockIdx.x;
  int t = row & (T_ - 1);
  int id = x[row];
#pragma unroll
  for (int j = 0; j < 3; ++j) {
    int c = threadIdx.x + j * 256;
    float v = emb[(size_t)id * C_ + c] + pos[(size_t)t * C_ + c];
    h[(size_t)row * C_ + c] = v;
    hb[(size_t)row * C_ + c] = __float2bfloat16(v);
  }
}

// ---------------------------------------------------------------------------
// Transpose + cast: W (K x N, f32) -> Wt (N x K, bf16)
// ---------------------------------------------------------------------------
__global__ void transpose_cast(const float* __restrict__ W,
                               __hip_bfloat16* __restrict__ Wt, int K, int N) {
  __shared__ float tile[32][33];
  int nb = blockIdx.x * 32, kb = blockIdx.y * 32;
  int tx = threadIdx.x, ty = threadIdx.y;  // 32 x 8
#pragma unroll
  for (int r = 0; r < 4; ++r)
    tile[ty + r * 8][tx] = W[(size_t)(kb + ty + r * 8) * N + nb + tx];
  __syncthreads();
#pragma unroll
  for (int r = 0; r < 4; ++r)
    Wt[(size_t)(nb + ty + r * 8) * K + kb + tx] =
        __float2bfloat16(tile[tx][ty + r * 8]);
}

// Two matrices of identical shape in one dispatch (z selects).
__global__ void transpose_cast2(const float* __restrict__ Wa,
                                __hip_bfloat16* __restrict__ Wta,
                                const float* __restrict__ Wb,
                                __hip_bfloat16* __restrict__ Wtb, int K, int N) {
  __shared__ float tile[32][33];
  const float* W = blockIdx.z ? Wb : Wa;
  __hip_bfloat16* Wt = blockIdx.z ? Wtb : Wta;
  int nb = blockIdx.x * 32, kb = blockIdx.y * 32;
  int tx = threadIdx.x, ty = threadIdx.y;  // 32 x 8
#pragma unroll
  for (int r = 0; r < 4; ++r)
    tile[ty + r * 8][tx] = W[(size_t)(kb + ty + r * 8) * N + nb + tx];
  __syncthreads();
#pragma unroll
  for (int r = 0; r < 4; ++r)
    Wt[(size_t)(nb + ty + r * 8) * K + kb + tx] =
        __float2bfloat16(tile[tx][ty + r * 8]);
}

// ---------------------------------------------------------------------------
// GEMM: C[M,N] = A[M,K](bf16) @ Bt[N,K](bf16)^T + bias, opt GELU, f32/bf16 out
// 128x128 tile, BK=32, 256 threads (4 waves, 2x2), mfma_f32_16x16x32_bf16.
// Depth-2 counted-vmcnt pipeline (T4): tiles s and s+1 always in flight;
// per step: s_waitcnt vmcnt(4) [tile s landed, s+1 flying] -> raw s_barrier
// -> compute(cur) -> raw s_barrier -> restage cur for tile s+2. Loads stay
// in flight ACROSS barriers; no vmcnt(0) drain except the peeled last step.
// Optional split-K via blockIdx.z (z=0 -> Cv (+bias), z=1 -> C2, raw).
// ---------------------------------------------------------------------------
template <int ACT_GELU, int OUT_BF16>
__global__ __launch_bounds__(256, 2) void gemm_bt(
    const __hip_bfloat16* __restrict__ A, const __hip_bfloat16* __restrict__ Bt,
    const float* __restrict__ bias, void* __restrict__ Cv,
    float* __restrict__ C2, int M, int N, int K) {
  __shared__ __align__(16) __hip_bfloat16 As[2][128 * 32];
  __shared__ __align__(16) __hip_bfloat16 Bs[2][128 * 32];
  const int tid = threadIdx.x;
  const int lane = tid & 63, wv = tid >> 6;
  const int lane4 = lane & 15, quad = lane >> 4;
  const int wr = wv >> 1, wc = wv & 1;
  const int bm = blockIdx.y * 128, bn = blockIdx.x * 128;

  const int kz = blockIdx.z;
  const int Ksub = K / gridDim.z;  // full K when gridDim.z == 1

  const int r0 = tid >> 2, kc0 = (tid & 3) * 8;
  const __hip_bfloat16* gA0 = A + (size_t)(bm + r0) * K + kz * Ksub + kc0;
  const __hip_bfloat16* gA1 = gA0 + (size_t)64 * K;
  const __hip_bfloat16* gB0 = Bt + (size_t)(bn + r0) * K + kz * Ksub + kc0;
  const __hip_bfloat16* gB1 = gB0 + (size_t)64 * K;

  auto stage = [&](int bsel, int k0) {
    async16(gA0 + k0, As[bsel] + tid * 8);
    async16(gA1 + k0, As[bsel] + (tid + 256) * 8);
    async16(gB0 + k0, Bs[bsel] + tid * 8);
    async16(gB1 + k0, Bs[bsel] + (tid + 256) * 8);
  };

  f32x4 acc[4][4] = {};

  auto compute = [&](int cur) {
    bf16x8 af[4], bfv[4];
#pragma unroll
    for (int i = 0; i < 4; ++i)
      af[i] =
          *(const bf16x8*)(As[cur] + (wr * 64 + i * 16 + lane4) * 32 + quad * 8);
#pragma unroll
    for (int j = 0; j < 4; ++j)
      bfv[j] =
          *(const bf16x8*)(Bs[cur] + (wc * 64 + j * 16 + lane4) * 32 + quad * 8);
#pragma unroll
    for (int i = 0; i < 4; ++i)
#pragma unroll
      for (int j = 0; j < 4; ++j)
        acc[i][j] = __builtin_amdgcn_mfma_f32_16x16x32_bf16(af[i], bfv[j],
                                                            acc[i][j], 0, 0, 0);
  };

  const int nsteps = Ksub / 32;  // >= 12 for all our shapes
  stage(0, 0);
  stage(1, 32);

  for (int s = 0; s < nsteps - 1; ++s) {
    // tile s fully landed (vmcnt retires in order; tile s+1 still in flight)
    asm volatile("s_waitcnt vmcnt(4)" ::: "memory");
    __builtin_amdgcn_s_barrier();
    __builtin_amdgcn_sched_barrier(0);
    compute(s & 1);
    __builtin_amdgcn_sched_barrier(0);
    __builtin_amdgcn_s_barrier();  // all waves done reading buf (s&1)
    __builtin_amdgcn_sched_barrier(0);
    if (s + 2 < nsteps) stage(s & 1, (s + 2) * 32);
  }
  asm volatile("s_waitcnt vmcnt(0)" ::: "memory");
  __builtin_amdgcn_s_barrier();
  __builtin_amdgcn_sched_barrier(0);
  compute((nsteps - 1) & 1);

  float* outf = (kz == 0) ? (float*)Cv : C2;
#pragma unroll
  for (int i = 0; i < 4; ++i) {
    int row0 = bm + wr * 64 + i * 16 + quad * 4;
#pragma unroll
    for (int j = 0; j < 4; ++j) {
      int col = bn + wc * 64 + j * 16 + lane4;
      float bv = (kz == 0) ? bias[col] : 0.f;
#pragma unroll
      for (int r = 0; r < 4; ++r) {
        float v = acc[i][j][r] + bv;
        if (ACT_GELU) v = gelu_f(v);
        size_t off = (size_t)(row0 + r) * N + col;
        if (OUT_BF16)
          ((__hip_bfloat16*)Cv)[off] = __float2bfloat16(v);
        else
          outf[off] = v;
      }
    }
  }
}

// ---------------------------------------------------------------------------
// MFMA flash attention, swapped-operand layout (S^T = K Q^T) so the online
// softmax is lane-local. One barrier per k-tile via double-buffered LDS.
// One q-tile per block (grid 16 x 96 = 1536 blocks -> 4 blocks/CU, LDS-
// bound); qt descending with blockIdx so heavy tiles are scheduled first
// and short-qt blocks backfill. setprio(1) around MFMA clusters (T5).
// ---------------------------------------------------------------------------
__global__ __launch_bounds__(256) void attn_mfma(
    const __hip_bfloat16* __restrict__ qkv, __hip_bfloat16* __restrict__ y) {
  __shared__ __align__(16) __hip_bfloat16 VtS[2][64][72];    // [buf][dim][key]
  __shared__ __align__(16) __hip_bfloat16 Ps[2][4][16][72];  // [buf][w][q][key]

  const int tid = threadIdx.x;
  const int lane = tid & 63, w = tid >> 6;
  const int lane4 = lane & 15, quad = lane >> 4;
  const int bh = blockIdx.y;
  const int b = bh / H_, hh = bh % H_;
  const unsigned short* qk16 = (const unsigned short*)qkv;
  const size_t base = (size_t)b * T_ * (3 * C_) + hh * D_HEAD;
  const size_t tile_stride = (size_t)64 * (3 * C_);

  union FragU { bf16x8 v; unsigned short s[8]; uint4 q; };

  // per-lane constant base offsets for K (A-frag rows) and V (raw rows)
  const unsigned short* kbase0 =
      qk16 + base + (size_t)lane4 * (3 * C_) + quad * 8;
  const unsigned short* vbase =
      qk16 + base + (size_t)lane * (3 * C_) + 2 * C_ + w * 16;

  int buf = 0;
  const int qt = gridDim.x - 1 - blockIdx.x;  // heavy tiles first

  // Q fragment (B operand), rows = qt*64 + w*16 + lane4, pre-scaled by 1/8
  FragU aq[2];
  {
    const unsigned short* qp =
        qk16 + base + (size_t)(qt * 64 + w * 16 + lane4) * (3 * C_) + C_ +
        quad * 8;
#pragma unroll
    for (int c = 0; c < 2; ++c) {
      FragU t;
      t.q = *(const uint4*)(qp + c * 32);
#pragma unroll
      for (int j = 0; j < 8; ++j) aq[c].s[j] = f2bf(bf2f(t.s[j]) * 0.125f);
    }
  }

  f32x4 o_acc[4] = {};  // O^T: o_acc[dt][r] = O[q=lane4][d=dt*16+quad*4+r]
  float m_r = -1e30f, l_r = 0.f;

  FragU kc[4][2];
  uint4 vc0, vc1;
  // preload tile 0
  {
    const unsigned short* kp = kbase0;
#pragma unroll
    for (int nt = 0; nt < 4; ++nt) {
      kc[nt][0].q = *(const uint4*)(kp + nt * 16 * (3 * C_));
      kc[nt][1].q = *(const uint4*)(kp + nt * 16 * (3 * C_) + 32);
    }
    vc0 = *(const uint4*)vbase;
    vc1 = *(const uint4*)(vbase + 8);
  }

  for (int kt = 0; kt <= qt; ++kt) {
    // --- issue prefetch for next tile (clamped; independent of compute) ---
    FragU kn[4][2];
    uint4 vn0, vn1;
    {
      int ktn = (kt < qt) ? kt + 1 : qt;
      const unsigned short* kp = kbase0 + (size_t)ktn * tile_stride;
#pragma unroll
      for (int nt = 0; nt < 4; ++nt) {
        kn[nt][0].q = *(const uint4*)(kp + nt * 16 * (3 * C_));
        kn[nt][1].q = *(const uint4*)(kp + nt * 16 * (3 * C_) + 32);
      }
      const unsigned short* vp = vbase + (size_t)ktn * tile_stride;
      vn0 = *(const uint4*)vp;
      vn1 = *(const uint4*)(vp + 8);
    }

    // --- S^T = K Q^T: s_acc[nt][r] = S[key=nt*16+quad*4+r][q=lane4] ---
    f32x4 s_acc[4] = {};
    __builtin_amdgcn_s_setprio(1);
#pragma unroll
    for (int nt = 0; nt < 4; ++nt) {
      s_acc[nt] = __builtin_amdgcn_mfma_f32_16x16x32_bf16(
          kc[nt][0].v, aq[0].v, s_acc[nt], 0, 0, 0);
      s_acc[nt] = __builtin_amdgcn_mfma_f32_16x16x32_bf16(
          kc[nt][1].v, aq[1].v, s_acc[nt], 0, 0, 0);
    }
    __builtin_amdgcn_s_setprio(0);

    // --- causal mask (diagonal tile only): key_loc > q_loc ---
    if (kt == qt) {
      int qloc = w * 16 + lane4;
#pragma unroll
      for (int nt = 0; nt < 4; ++nt) {
        int k0loc = nt * 16 + quad * 4;
#pragma unroll
        for (int r = 0; r < 4; ++r)
          if (k0loc + r > qloc) s_acc[nt][r] = -1e30f;
      }
    }

    // --- online softmax: lane-local tree + 2 shfls (quad combine) ---
    float a0 = fmaxf(fmaxf(s_acc[0][0], s_acc[0][1]),
                     fmaxf(s_acc[0][2], s_acc[0][3]));
    float a1 = fmaxf(fmaxf(s_acc[1][0], s_acc[1][1]),
                     fmaxf(s_acc[1][2], s_acc[1][3]));
    float a2 = fmaxf(fmaxf(s_acc[2][0], s_acc[2][1]),
                     fmaxf(s_acc[2][2], s_acc[2][3]));
    float a3 = fmaxf(fmaxf(s_acc[3][0], s_acc[3][1]),
                     fmaxf(s_acc[3][2], s_acc[3][3]));
    float tm = fmaxf(fmaxf(a0, a1), fmaxf(a2, a3));
    tm = fmaxf(tm, __shfl_xor(tm, 16));
    tm = fmaxf(tm, __shfl_xor(tm, 32));
    float mn = fmaxf(m_r, tm);
    float alpha = __expf(m_r - mn);
    m_r = mn;

    float sr = 0.f;
#pragma unroll
    for (int nt = 0; nt < 4; ++nt) {
      float p0 = __expf(s_acc[nt][0] - mn);
      float p1 = __expf(s_acc[nt][1] - mn);
      float p2 = __expf(s_acc[nt][2] - mn);
      float p3 = __expf(s_acc[nt][3] - mn);
      sr += (p0 + p1) + (p2 + p3);
      union { unsigned short s[4]; uint2 u; } pk;
      pk.s[0] = f2bf(p0);
      pk.s[1] = f2bf(p1);
      pk.s[2] = f2bf(p2);
      pk.s[3] = f2bf(p3);
      *(uint2*)&Ps[buf][w][lane4][nt * 16 + quad * 4] = pk.u;
    }
    sr += __shfl_xor(sr, 16);
    sr += __shfl_xor(sr, 32);
    l_r = l_r * alpha + sr;

    // --- rescale O^T by alpha (single per-lane scalar) ---
#pragma unroll
    for (int dt = 0; dt < 4; ++dt)
#pragma unroll
      for (int r = 0; r < 4; ++r) o_acc[dt][r] *= alpha;

    // --- write V^T to LDS (wave w covers dims w*16..w*16+15) ---
    {
      const unsigned short* vs = (const unsigned short*)&vc0;
#pragma unroll
      for (int j = 0; j < 8; ++j)
        *(unsigned short*)&VtS[buf][w * 16 + j][lane] = vs[j];
      vs = (const unsigned short*)&vc1;
#pragma unroll
      for (int j = 0; j < 8; ++j)
        *(unsigned short*)&VtS[buf][w * 16 + 8 + j][lane] = vs[j];
    }

    __syncthreads();  // buf writes visible; prior buf^1 reads already done

    // --- O^T += V^T P : mfma(A=V^T frag, B=P frag) ---
    FragU pp0, pp1;
    pp0.v = *(const bf16x8*)&Ps[buf][w][lane4][quad * 8];
    pp1.v = *(const bf16x8*)&Ps[buf][w][lane4][32 + quad * 8];
    __builtin_amdgcn_s_setprio(1);
#pragma unroll
    for (int dt = 0; dt < 4; ++dt) {
      bf16x8 bv0 = *(const bf16x8*)&VtS[buf][dt * 16 + lane4][quad * 8];
      bf16x8 bv1 = *(const bf16x8*)&VtS[buf][dt * 16 + lane4][32 + quad * 8];
      o_acc[dt] = __builtin_amdgcn_mfma_f32_16x16x32_bf16(bv0, pp0.v,
                                                          o_acc[dt], 0, 0, 0);
      o_acc[dt] = __builtin_amdgcn_mfma_f32_16x16x32_bf16(bv1, pp1.v,
                                                          o_acc[dt], 0, 0, 0);
    }
    __builtin_amdgcn_s_setprio(0);

    // --- rotate prefetched regs into current; flip LDS buffer ---
#pragma unroll
    for (int nt = 0; nt < 4; ++nt) {
      kc[nt][0] = kn[nt][0];
      kc[nt][1] = kn[nt][1];
    }
    vc0 = vn0;
    vc1 = vn1;
    buf ^= 1;
  }

  // --- epilogue: lane owns query lane4, dims dt*16+quad*4+{0..3} ---
  float invl = 1.f / l_r;
  int qrow = qt * 64 + w * 16 + lane4;
  unsigned short* yp =
      (unsigned short*)y + (size_t)(b * T_ + qrow) * C_ + hh * D_HEAD;
#pragma unroll
  for (int dt = 0; dt < 4; ++dt) {
    union { unsigned short s[4]; uint2 u; } ok;
#pragma unroll
    for (int r = 0; r < 4; ++r) ok.s[r] = f2bf(o_acc[dt][r] * invl);
    *(uint2*)(yp + dt * 16 + quad * 4) = ok.u;
  }
}

// ---------------------------------------------------------------------------
// h = h + LayerNorm(z0 + z1) * g + beta ; also write bf16 copy of updated h.
// (z1 is the split-K partial; both read as full rows.)
// ---------------------------------------------------------------------------
__global__ __launch_bounds__(256) void resid_ln2(
    float* __restrict__ h, const float* __restrict__ z0,
    const float* __restrict__ z1, const float* __restrict__ g,
    const float* __restrict__ be, __hip_bfloat16* __restrict__ hb) {
  int row = blockIdx.x;
  int tid = threadIdx.x;
  const float* zr0 = z0 + (size_t)row * C_;
  const float* zr1 = z1 + (size_t)row * C_;
  float v[3], s = 0.f, s2 = 0.f;
#pragma unroll
  for (int j = 0; j < 3; ++j) {
    int c = tid + 256 * j;
    v[j] = zr0[c] + zr1[c];
    s += v[j];
    s2 += v[j] * v[j];
  }
#pragma unroll
  for (int msk = 1; msk < 64; msk <<= 1) {
    s += __shfl_xor(s, msk);
    s2 += __shfl_xor(s2, msk);
  }
  __shared__ float red[8];
  int w = tid >> 6;
  if ((tid & 63) == 0) { red[w] = s; red[4 + w] = s2; }
  __syncthreads();
  s = red[0] + red[1] + red[2] + red[3];
  s2 = red[4] + red[5] + red[6] + red[7];
  float mu = s * (1.f / C_);
  float var = s2 * (1.f / C_) - mu * mu;
  float rstd = rsqrtf(var + 1e-5f);
  float* hr = h + (size_t)row * C_;
  __hip_bfloat16* hbr = hb + (size_t)row * C_;
#pragma unroll
  for (int j = 0; j < 3; ++j) {
    int c = tid + 256 * j;
    float nv = hr[c] + (v[j] - mu) * rstd * g[c] + be[c];
    hr[c] = nv;
    hbr[c] = __float2bfloat16(nv);
  }
}

// ---------------------------------------------------------------------------
extern "C" void kernel_launch(void* const* d_in, const int* in_sizes, int n_in,
                              void* d_out, int out_size, void* d_ws,
                              size_t ws_size, hipStream_t stream) {
  const int* x = (const int*)d_in[0];
  const float* embed = (const float*)d_in[1];
  const float* pos = (const float*)d_in[2];
  const float* Wqkv = (const float*)d_in[3];
  const float* bqkv = (const float*)d_in[4];
  const float* W1a = (const float*)d_in[5];
  const float* b1a = (const float*)d_in[6];
  const float* W2a = (const float*)d_in[7];
  const float* b2a = (const float*)d_in[8];
  const float* g1 = (const float*)d_in[9];
  const float* be1 = (const float*)d_in[10];
  const float* W1b = (const float*)d_in[11];
  const float* b1b = (const float*)d_in[12];
  const float* W2b = (const float*)d_in[13];
  const float* b2b = (const float*)d_in[14];
  const float* g2 = (const float*)d_in[15];
  const float* be2 = (const float*)d_in[16];
  const float* lmW = (const float*)d_in[17];
  const float* lmb = (const float*)d_in[18];
  float* out = (float*)d_out;

  char* p = (char*)d_ws;
  auto alloc = [&](size_t bytes) {
    void* r = (void*)p;
    p += (bytes + 255) & ~(size_t)255;
    return r;
  };
  float* h = (float*)alloc((size_t)M_ * C_ * 4);
  __hip_bfloat16* hb = (__hip_bfloat16*)alloc((size_t)M_ * C_ * 2);
  __hip_bfloat16* qkv = (__hip_bfloat16*)alloc((size_t)M_ * 3 * C_ * 2);
  __hip_bfloat16* ybuf = (__hip_bfloat16*)alloc((size_t)M_ * C_ * 2);
  __hip_bfloat16* ubuf = (__hip_bfloat16*)alloc((size_t)M_ * FF_ * 2);
  float* zbuf = (float*)alloc((size_t)M_ * C_ * 4);
  __hip_bfloat16* Wtqkv = (__hip_bfloat16*)alloc((size_t)(3 * C_) * C_ * 2);
  __hip_bfloat16* Wt1a = (__hip_bfloat16*)alloc((size_t)FF_ * C_ * 2);
  __hip_bfloat16* Wt1b = (__hip_bfloat16*)alloc((size_t)FF_ * C_ * 2);
  __hip_bfloat16* Wt2a = (__hip_bfloat16*)alloc((size_t)C_ * FF_ * 2);
  __hip_bfloat16* Wt2b = (__hip_bfloat16*)alloc((size_t)C_ * FF_ * 2);
  // split-K partial for FFN2: reuse qkv region (dead after attn_mfma each
  // layer; 37.7 MB >= 25.2 MB needed; rewritten by next layer's QKV gemm).
  float* zpart = (float*)qkv;

  dim3 blk256(256);
  embed_kernel<<<M_, blk256, 0, stream>>>(x, embed, pos, h, hb);

  for (int l = 0; l < L_; ++l) {
    // all weight transposes for this layer up front (independent of h)
    transpose_cast<<<dim3(3 * C_ / 32, C_ / 32), dim3(32, 8), 0, stream>>>(
        Wqkv + (size_t)l * C_ * 3 * C_, Wtqkv, C_, 3 * C_);
    transpose_cast2<<<dim3(FF_ / 32, C_ / 32, 2), dim3(32, 8), 0, stream>>>(
        W1a + (size_t)l * C_ * FF_, Wt1a, W1b + (size_t)l * C_ * FF_, Wt1b,
        C_, FF_);
    transpose_cast2<<<dim3(C_ / 32, FF_ / 32, 2), dim3(32, 8), 0, stream>>>(
        W2a + (size_t)l * FF_ * C_, Wt2a, W2b + (size_t)l * FF_ * C_, Wt2b,
        FF_, C_);

    gemm_bt<0, 1><<<dim3(3 * C_ / 128, M_ / 128), blk256, 0, stream>>>(
        hb, Wtqkv, bqkv + (size_t)l * 3 * C_, qkv, nullptr, M_, 3 * C_, C_);
    attn_mfma<<<dim3(T_ / 64, B_ * H_), blk256, 0, stream>>>(qkv, ybuf);
    gemm_bt<1, 1><<<dim3(FF_ / 128, M_ / 128), blk256, 0, stream>>>(
        ybuf, Wt1a, b1a + (size_t)l * FF_, ubuf, nullptr, M_, FF_, C_);
    gemm_bt<0, 0><<<dim3(C_ / 128, M_ / 128, 2), blk256, 0, stream>>>(
        ubuf, Wt2a, b2a + (size_t)l * C_, zbuf, zpart, M_, C_, FF_);
    resid_ln2<<<M_, blk256, 0, stream>>>(h, zbuf, zpart, g1 + (size_t)l * C_,
                                         be1 + (size_t)l * C_, hb);
    gemm_bt<1, 1><<<dim3(FF_ / 128, M_ / 128), blk256, 0, stream>>>(
        hb, Wt1b, b1b + (size_t)l * FF_, ubuf, nullptr, M_, FF_, C_);
    gemm_bt<0, 0><<<dim3(C_ / 128, M_ / 128, 2), blk256, 0, stream>>>(
        ubuf, Wt2b, b2b + (size_t)l * C_, zbuf, zpart, M_, C_, FF_);
    resid_ln2<<<M_, blk256, 0, stream>>>(h, zbuf, zpart, g2 + (size_t)l * C_,
                                         be2 + (size_t)l * C_, hb);
  }

  transpose_cast<<<dim3(V_ / 32, C_ / 32), dim3(32, 8), 0, stream>>>(
      lmW, Wtqkv, C_, V_);
  gemm_bt<0, 0><<<dim3(V_ / 128, M_ / 128), blk256, 0, stream>>>(
      hb, Wtqkv, lmb, out, nullptr, M_, V_, C_);
}

// Round 6
// 3393.800 us; speedup vs baseline: 1.1575x; 1.1575x over previous
//
#include <hip/hip_runtime.h>
#include <hip/hip_bf16.h>

#define L_ 8
#define B_ 8
#define T_ 1024
#define C_ 768
#define H_ 12
#define D_HEAD 64
#define V_ 1024
#define FF_ 3072
#define M_ (B_ * T_)  // 8192 rows

typedef __bf16 bf16x8 __attribute__((ext_vector_type(8)));
typedef float f32x4 __attribute__((ext_vector_type(4)));

typedef const __attribute__((address_space(1))) void* as1cvp;
typedef __attribute__((address_space(3))) void* as3vp;

__device__ __forceinline__ void async16(const void* g, void* l) {
  __builtin_amdgcn_global_load_lds((as1cvp)g, (as3vp)l, 16, 0, 0);
}

__device__ __forceinline__ float bf2f(unsigned short u) {
  union { unsigned u32; float f; } c; c.u32 = ((unsigned)u) << 16; return c.f;
}

__device__ __forceinline__ unsigned short f2bf(float f) {
  __hip_bfloat16 h = __float2bfloat16(f);
  return *(unsigned short*)&h;
}

// tanh-form GELU: x * sigmoid(2*0.7978845608*(x + 0.044715 x^3)).
// Max |err| vs erf-GELU ~1e-3; negligible after bf16 store + W2 contraction.
__device__ __forceinline__ float gelu_f(float x) {
  float u2 = x * (1.5957691216f + 0.0713548162f * x * x);
  return x / (1.f + __expf(-u2));
}

// ---------------------------------------------------------------------------
// Embedding: h[row, c] = embed[x[row]][c] + pos[row % T][c]; also bf16 copy.
// ---------------------------------------------------------------------------
__global__ __launch_bounds__(256) void embed_kernel(
    const int* __restrict__ x, const float* __restrict__ emb,
    const float* __restrict__ pos, float* __restrict__ h,
    __hip_bfloat16* __restrict__ hb) {
  int row = blockIdx.x;
  int t = row & (T_ - 1);
  int id = x[row];
#pragma unroll
  for (int j = 0; j < 3; ++j) {
    int c = threadIdx.x + j * 256;
    float v = emb[(size_t)id * C_ + c] + pos[(size_t)t * C_ + c];
    h[(size_t)row * C_ + c] = v;
    hb[(size_t)row * C_ + c] = __float2bfloat16(v);
  }
}

// ---------------------------------------------------------------------------
// Transpose + cast: W (K x N, f32) -> Wt (N x K, bf16)
// ---------------------------------------------------------------------------
__global__ void transpose_cast(const float* __restrict__ W,
                               __hip_bfloat16* __restrict__ Wt, int K, int N) {
  __shared__ float tile[32][33];
  int nb = blockIdx.x * 32, kb = blockIdx.y * 32;
  int tx = threadIdx.x, ty = threadIdx.y;  // 32 x 8
#pragma unroll
  for (int r = 0; r < 4; ++r)
    tile[ty + r * 8][tx] = W[(size_t)(kb + ty + r * 8) * N + nb + tx];
  __syncthreads();
#pragma unroll
  for (int r = 0; r < 4; ++r)
    Wt[(size_t)(nb + ty + r * 8) * K + kb + tx] =
        __float2bfloat16(tile[tx][ty + r * 8]);
}

// Two matrices of identical shape in one dispatch (z selects).
__global__ void transpose_cast2(const float* __restrict__ Wa,
                                __hip_bfloat16* __restrict__ Wta,
                                const float* __restrict__ Wb,
                                __hip_bfloat16* __restrict__ Wtb, int K, int N) {
  __shared__ float tile[32][33];
  const float* W = blockIdx.z ? Wb : Wa;
  __hip_bfloat16* Wt = blockIdx.z ? Wtb : Wta;
  int nb = blockIdx.x * 32, kb = blockIdx.y * 32;
  int tx = threadIdx.x, ty = threadIdx.y;  // 32 x 8
#pragma unroll
  for (int r = 0; r < 4; ++r)
    tile[ty + r * 8][tx] = W[(size_t)(kb + ty + r * 8) * N + nb + tx];
  __syncthreads();
#pragma unroll
  for (int r = 0; r < 4; ++r)
    Wt[(size_t)(nb + ty + r * 8) * K + kb + tx] =
        __float2bfloat16(tile[tx][ty + r * 8]);
}

// ---------------------------------------------------------------------------
// GEMM: C[M,N] = A[M,K](bf16) @ Bt[N,K](bf16)^T + bias, opt GELU, f32/bf16 out
// 128x128 tile, BK=32, 256 threads (4 waves, 2x2), mfma_f32_16x16x32_bf16.
// Depth-2 counted-vmcnt pipeline (T4). XCD-aware block remap (T1): each XCD
// gets a contiguous chunk of row-major tile ids -> A-panel L2 locality.
// Optional split-K via blockIdx.z (z=0 -> Cv (+bias), z=1 -> C2, raw).
// ---------------------------------------------------------------------------
template <int ACT_GELU, int OUT_BF16>
__global__ __launch_bounds__(256, 2) void gemm_bt(
    const __hip_bfloat16* __restrict__ A, const __hip_bfloat16* __restrict__ Bt,
    const float* __restrict__ bias, void* __restrict__ Cv,
    float* __restrict__ C2, int M, int N, int K) {
  __shared__ __align__(16) __hip_bfloat16 As[2][128 * 32];
  __shared__ __align__(16) __hip_bfloat16 Bs[2][128 * 32];
  const int tid = threadIdx.x;
  const int lane = tid & 63, wv = tid >> 6;
  const int lane4 = lane & 15, quad = lane >> 4;
  const int wr = wv >> 1, wc = wv & 1;

  // XCD-aware remap: dispatch id d runs on XCD d%8; map so each XCD owns a
  // contiguous chunk of logical row-major tile ids (all our grids are %8==0).
  const int nx = gridDim.x;
  const int nwg = nx * gridDim.y;
  int did = blockIdx.x + nx * blockIdx.y;
  int lid = ((nwg & 7) == 0) ? ((did & 7) * (nwg >> 3) + (did >> 3)) : did;
  const int bm = (lid / nx) * 128, bn = (lid % nx) * 128;

  const int kz = blockIdx.z;
  const int Ksub = K / gridDim.z;  // full K when gridDim.z == 1

  const int r0 = tid >> 2, kc0 = (tid & 3) * 8;
  const __hip_bfloat16* gA0 = A + (size_t)(bm + r0) * K + kz * Ksub + kc0;
  const __hip_bfloat16* gA1 = gA0 + (size_t)64 * K;
  const __hip_bfloat16* gB0 = Bt + (size_t)(bn + r0) * K + kz * Ksub + kc0;
  const __hip_bfloat16* gB1 = gB0 + (size_t)64 * K;

  auto stage = [&](int bsel, int k0) {
    async16(gA0 + k0, As[bsel] + tid * 8);
    async16(gA1 + k0, As[bsel] + (tid + 256) * 8);
    async16(gB0 + k0, Bs[bsel] + tid * 8);
    async16(gB1 + k0, Bs[bsel] + (tid + 256) * 8);
  };

  f32x4 acc[4][4] = {};

  auto compute = [&](int cur) {
    bf16x8 af[4], bfv[4];
#pragma unroll
    for (int i = 0; i < 4; ++i)
      af[i] =
          *(const bf16x8*)(As[cur] + (wr * 64 + i * 16 + lane4) * 32 + quad * 8);
#pragma unroll
    for (int j = 0; j < 4; ++j)
      bfv[j] =
          *(const bf16x8*)(Bs[cur] + (wc * 64 + j * 16 + lane4) * 32 + quad * 8);
#pragma unroll
    for (int i = 0; i < 4; ++i)
#pragma unroll
      for (int j = 0; j < 4; ++j)
        acc[i][j] = __builtin_amdgcn_mfma_f32_16x16x32_bf16(af[i], bfv[j],
                                                            acc[i][j], 0, 0, 0);
  };

  const int nsteps = Ksub / 32;  // >= 12 for all our shapes
  stage(0, 0);
  stage(1, 32);

  for (int s = 0; s < nsteps - 1; ++s) {
    // tile s fully landed (vmcnt retires in order; tile s+1 still in flight)
    asm volatile("s_waitcnt vmcnt(4)" ::: "memory");
    __builtin_amdgcn_s_barrier();
    __builtin_amdgcn_sched_barrier(0);
    compute(s & 1);
    __builtin_amdgcn_sched_barrier(0);
    __builtin_amdgcn_s_barrier();  // all waves done reading buf (s&1)
    __builtin_amdgcn_sched_barrier(0);
    if (s + 2 < nsteps) stage(s & 1, (s + 2) * 32);
  }
  asm volatile("s_waitcnt vmcnt(0)" ::: "memory");
  __builtin_amdgcn_s_barrier();
  __builtin_amdgcn_sched_barrier(0);
  compute((nsteps - 1) & 1);

  float* outf = (kz == 0) ? (float*)Cv : C2;
#pragma unroll
  for (int i = 0; i < 4; ++i) {
    int row0 = bm + wr * 64 + i * 16 + quad * 4;
#pragma unroll
    for (int j = 0; j < 4; ++j) {
      int col = bn + wc * 64 + j * 16 + lane4;
      float bv = (kz == 0) ? bias[col] : 0.f;
#pragma unroll
      for (int r = 0; r < 4; ++r) {
        float v = acc[i][j][r] + bv;
        if (ACT_GELU) v = gelu_f(v);
        size_t off = (size_t)(row0 + r) * N + col;
        if (OUT_BF16)
          ((__hip_bfloat16*)Cv)[off] = __float2bfloat16(v);
        else
          outf[off] = v;
      }
    }
  }
}

// ---------------------------------------------------------------------------
// MFMA flash attention, swapped-operand layout (S^T = K Q^T) so the online
// softmax is lane-local. One barrier per k-tile via double-buffered LDS.
// Each block processes the complementary q-tile pair (qt, 15-qt): uniform
// 17 tile-units/block, 768 blocks all co-resident (3/CU). XCD-aware remap:
// each XCD owns 12 heads -> their K/V (3 MB) fits the 4 MB per-XCD L2.
// ---------------------------------------------------------------------------
__global__ __launch_bounds__(256) void attn_mfma(
    const __hip_bfloat16* __restrict__ qkv, __hip_bfloat16* __restrict__ y) {
  __shared__ __align__(16) __hip_bfloat16 VtS[2][64][72];    // [buf][dim][key]
  __shared__ __align__(16) __hip_bfloat16 Ps[2][4][16][72];  // [buf][w][q][key]

  const int tid = threadIdx.x;
  const int lane = tid & 63, w = tid >> 6;
  const int lane4 = lane & 15, quad = lane >> 4;

  // XCD-aware remap: dispatch id d -> XCD d%8. Chunk the logical id space so
  // XCD k gets logical ids [k*96, (k+1)*96) = 12 consecutive heads.
  const int nxq = gridDim.x;                       // 8 q-tile pairs
  const int nwg = nxq * gridDim.y;                 // 768
  const int did = blockIdx.x + nxq * blockIdx.y;
  const int lid = (did & 7) * (nwg >> 3) + (did >> 3);
  const int qpair = lid % nxq;
  const int bh = lid / nxq;

  const int b = bh / H_, hh = bh % H_;
  const unsigned short* qk16 = (const unsigned short*)qkv;
  const size_t base = (size_t)b * T_ * (3 * C_) + hh * D_HEAD;
  const size_t tile_stride = (size_t)64 * (3 * C_);
  const int NTILE = T_ / 64;  // 16

  union FragU { bf16x8 v; unsigned short s[8]; uint4 q; };

  // per-lane constant base offsets for K (A-frag rows) and V (raw rows)
  const unsigned short* kbase0 =
      qk16 + base + (size_t)lane4 * (3 * C_) + quad * 8;
  const unsigned short* vbase =
      qk16 + base + (size_t)lane * (3 * C_) + 2 * C_ + w * 16;

  int buf = 0;

  for (int qi = 0; qi < 2; ++qi) {
    const int qt = qi ? qpair : (NTILE - 1 - qpair);

    // Q fragment (B operand), rows = qt*64 + w*16 + lane4, pre-scaled by 1/8
    FragU aq[2];
    {
      const unsigned short* qp =
          qk16 + base + (size_t)(qt * 64 + w * 16 + lane4) * (3 * C_) + C_ +
          quad * 8;
#pragma unroll
      for (int c = 0; c < 2; ++c) {
        FragU t;
        t.q = *(const uint4*)(qp + c * 32);
#pragma unroll
        for (int j = 0; j < 8; ++j) aq[c].s[j] = f2bf(bf2f(t.s[j]) * 0.125f);
      }
    }

    f32x4 o_acc[4] = {};  // O^T: o_acc[dt][r] = O[q=lane4][d=dt*16+quad*4+r]
    float m_r = -1e30f, l_r = 0.f;

    FragU kc[4][2];
    uint4 vc0, vc1;
    // preload tile 0
    {
      const unsigned short* kp = kbase0;
#pragma unroll
      for (int nt = 0; nt < 4; ++nt) {
        kc[nt][0].q = *(const uint4*)(kp + nt * 16 * (3 * C_));
        kc[nt][1].q = *(const uint4*)(kp + nt * 16 * (3 * C_) + 32);
      }
      vc0 = *(const uint4*)vbase;
      vc1 = *(const uint4*)(vbase + 8);
    }

    for (int kt = 0; kt <= qt; ++kt) {
      // --- issue prefetch for next tile (clamped; independent of compute) ---
      FragU kn[4][2];
      uint4 vn0, vn1;
      {
        int ktn = (kt < qt) ? kt + 1 : qt;
        const unsigned short* kp = kbase0 + (size_t)ktn * tile_stride;
#pragma unroll
        for (int nt = 0; nt < 4; ++nt) {
          kn[nt][0].q = *(const uint4*)(kp + nt * 16 * (3 * C_));
          kn[nt][1].q = *(const uint4*)(kp + nt * 16 * (3 * C_) + 32);
        }
        const unsigned short* vp = vbase + (size_t)ktn * tile_stride;
        vn0 = *(const uint4*)vp;
        vn1 = *(const uint4*)(vp + 8);
      }

      // --- S^T = K Q^T: s_acc[nt][r] = S[key=nt*16+quad*4+r][q=lane4] ---
      f32x4 s_acc[4] = {};
#pragma unroll
      for (int nt = 0; nt < 4; ++nt) {
        s_acc[nt] = __builtin_amdgcn_mfma_f32_16x16x32_bf16(
            kc[nt][0].v, aq[0].v, s_acc[nt], 0, 0, 0);
        s_acc[nt] = __builtin_amdgcn_mfma_f32_16x16x32_bf16(
            kc[nt][1].v, aq[1].v, s_acc[nt], 0, 0, 0);
      }

      // --- causal mask (diagonal tile only): key_loc > q_loc ---
      if (kt == qt) {
        int qloc = w * 16 + lane4;
#pragma unroll
        for (int nt = 0; nt < 4; ++nt) {
          int k0loc = nt * 16 + quad * 4;
#pragma unroll
          for (int r = 0; r < 4; ++r)
            if (k0loc + r > qloc) s_acc[nt][r] = -1e30f;
        }
      }

      // --- online softmax: lane-local tree + 2 shfls (quad combine) ---
      float a0 = fmaxf(fmaxf(s_acc[0][0], s_acc[0][1]),
                       fmaxf(s_acc[0][2], s_acc[0][3]));
      float a1 = fmaxf(fmaxf(s_acc[1][0], s_acc[1][1]),
                       fmaxf(s_acc[1][2], s_acc[1][3]));
      float a2 = fmaxf(fmaxf(s_acc[2][0], s_acc[2][1]),
                       fmaxf(s_acc[2][2], s_acc[2][3]));
      float a3 = fmaxf(fmaxf(s_acc[3][0], s_acc[3][1]),
                       fmaxf(s_acc[3][2], s_acc[3][3]));
      float tm = fmaxf(fmaxf(a0, a1), fmaxf(a2, a3));
      tm = fmaxf(tm, __shfl_xor(tm, 16));
      tm = fmaxf(tm, __shfl_xor(tm, 32));
      float mn = fmaxf(m_r, tm);
      float alpha = __expf(m_r - mn);
      m_r = mn;

      float sr = 0.f;
#pragma unroll
      for (int nt = 0; nt < 4; ++nt) {
        float p0 = __expf(s_acc[nt][0] - mn);
        float p1 = __expf(s_acc[nt][1] - mn);
        float p2 = __expf(s_acc[nt][2] - mn);
        float p3 = __expf(s_acc[nt][3] - mn);
        sr += (p0 + p1) + (p2 + p3);
        union { unsigned short s[4]; uint2 u; } pk;
        pk.s[0] = f2bf(p0);
        pk.s[1] = f2bf(p1);
        pk.s[2] = f2bf(p2);
        pk.s[3] = f2bf(p3);
        *(uint2*)&Ps[buf][w][lane4][nt * 16 + quad * 4] = pk.u;
      }
      sr += __shfl_xor(sr, 16);
      sr += __shfl_xor(sr, 32);
      l_r = l_r * alpha + sr;

      // --- rescale O^T by alpha (single per-lane scalar) ---
#pragma unroll
      for (int dt = 0; dt < 4; ++dt)
#pragma unroll
        for (int r = 0; r < 4; ++r) o_acc[dt][r] *= alpha;

      // --- write V^T to LDS (wave w covers dims w*16..w*16+15) ---
      {
        const unsigned short* vs = (const unsigned short*)&vc0;
#pragma unroll
        for (int j = 0; j < 8; ++j)
          *(unsigned short*)&VtS[buf][w * 16 + j][lane] = vs[j];
        vs = (const unsigned short*)&vc1;
#pragma unroll
        for (int j = 0; j < 8; ++j)
          *(unsigned short*)&VtS[buf][w * 16 + 8 + j][lane] = vs[j];
      }

      __syncthreads();  // buf writes visible; prior buf^1 reads already done

      // --- O^T += V^T P : mfma(A=V^T frag, B=P frag) ---
      FragU pp0, pp1;
      pp0.v = *(const bf16x8*)&Ps[buf][w][lane4][quad * 8];
      pp1.v = *(const bf16x8*)&Ps[buf][w][lane4][32 + quad * 8];
#pragma unroll
      for (int dt = 0; dt < 4; ++dt) {
        bf16x8 bv0 = *(const bf16x8*)&VtS[buf][dt * 16 + lane4][quad * 8];
        bf16x8 bv1 = *(const bf16x8*)&VtS[buf][dt * 16 + lane4][32 + quad * 8];
        o_acc[dt] = __builtin_amdgcn_mfma_f32_16x16x32_bf16(bv0, pp0.v,
                                                            o_acc[dt], 0, 0, 0);
        o_acc[dt] = __builtin_amdgcn_mfma_f32_16x16x32_bf16(bv1, pp1.v,
                                                            o_acc[dt], 0, 0, 0);
      }

      // --- rotate prefetched regs into current; flip LDS buffer ---
#pragma unroll
      for (int nt = 0; nt < 4; ++nt) {
        kc[nt][0] = kn[nt][0];
        kc[nt][1] = kn[nt][1];
      }
      vc0 = vn0;
      vc1 = vn1;
      buf ^= 1;
    }

    // --- epilogue: lane owns query lane4, dims dt*16+quad*4+{0..3} ---
    float invl = 1.f / l_r;
    int qrow = qt * 64 + w * 16 + lane4;
    unsigned short* yp =
        (unsigned short*)y + (size_t)(b * T_ + qrow) * C_ + hh * D_HEAD;
#pragma unroll
    for (int dt = 0; dt < 4; ++dt) {
      union { unsigned short s[4]; uint2 u; } ok;
#pragma unroll
      for (int r = 0; r < 4; ++r) ok.s[r] = f2bf(o_acc[dt][r] * invl);
      *(uint2*)(yp + dt * 16 + quad * 4) = ok.u;
    }
  }
}

// ---------------------------------------------------------------------------
// h = h + LayerNorm(z0 + z1) * g + beta ; also write bf16 copy of updated h.
// (z1 is the split-K partial; both read as full rows.)
// ---------------------------------------------------------------------------
__global__ __launch_bounds__(256) void resid_ln2(
    float* __restrict__ h, const float* __restrict__ z0,
    const float* __restrict__ z1, const float* __restrict__ g,
    const float* __restrict__ be, __hip_bfloat16* __restrict__ hb) {
  int row = blockIdx.x;
  int tid = threadIdx.x;
  const float* zr0 = z0 + (size_t)row * C_;
  const float* zr1 = z1 + (size_t)row * C_;
  float v[3], s = 0.f, s2 = 0.f;
#pragma unroll
  for (int j = 0; j < 3; ++j) {
    int c = tid + 256 * j;
    v[j] = zr0[c] + zr1[c];
    s += v[j];
    s2 += v[j] * v[j];
  }
#pragma unroll
  for (int msk = 1; msk < 64; msk <<= 1) {
    s += __shfl_xor(s, msk);
    s2 += __shfl_xor(s2, msk);
  }
  __shared__ float red[8];
  int w = tid >> 6;
  if ((tid & 63) == 0) { red[w] = s; red[4 + w] = s2; }
  __syncthreads();
  s = red[0] + red[1] + red[2] + red[3];
  s2 = red[4] + red[5] + red[6] + red[7];
  float mu = s * (1.f / C_);
  float var = s2 * (1.f / C_) - mu * mu;
  float rstd = rsqrtf(var + 1e-5f);
  float* hr = h + (size_t)row * C_;
  __hip_bfloat16* hbr = hb + (size_t)row * C_;
#pragma unroll
  for (int j = 0; j < 3; ++j) {
    int c = tid + 256 * j;
    float nv = hr[c] + (v[j] - mu) * rstd * g[c] + be[c];
    hr[c] = nv;
    hbr[c] = __float2bfloat16(nv);
  }
}

// ---------------------------------------------------------------------------
extern "C" void kernel_launch(void* const* d_in, const int* in_sizes, int n_in,
                              void* d_out, int out_size, void* d_ws,
                              size_t ws_size, hipStream_t stream) {
  const int* x = (const int*)d_in[0];
  const float* embed = (const float*)d_in[1];
  const float* pos = (const float*)d_in[2];
  const float* Wqkv = (const float*)d_in[3];
  const float* bqkv = (const float*)d_in[4];
  const float* W1a = (const float*)d_in[5];
  const float* b1a = (const float*)d_in[6];
  const float* W2a = (const float*)d_in[7];
  const float* b2a = (const float*)d_in[8];
  const float* g1 = (const float*)d_in[9];
  const float* be1 = (const float*)d_in[10];
  const float* W1b = (const float*)d_in[11];
  const float* b1b = (const float*)d_in[12];
  const float* W2b = (const float*)d_in[13];
  const float* b2b = (const float*)d_in[14];
  const float* g2 = (const float*)d_in[15];
  const float* be2 = (const float*)d_in[16];
  const float* lmW = (const float*)d_in[17];
  const float* lmb = (const float*)d_in[18];
  float* out = (float*)d_out;

  char* p = (char*)d_ws;
  auto alloc = [&](size_t bytes) {
    void* r = (void*)p;
    p += (bytes + 255) & ~(size_t)255;
    return r;
  };
  float* h = (float*)alloc((size_t)M_ * C_ * 4);
  __hip_bfloat16* hb = (__hip_bfloat16*)alloc((size_t)M_ * C_ * 2);
  __hip_bfloat16* qkv = (__hip_bfloat16*)alloc((size_t)M_ * 3 * C_ * 2);
  __hip_bfloat16* ybuf = (__hip_bfloat16*)alloc((size_t)M_ * C_ * 2);
  __hip_bfloat16* ubuf = (__hip_bfloat16*)alloc((size_t)M_ * FF_ * 2);
  float* zbuf = (float*)alloc((size_t)M_ * C_ * 4);
  __hip_bfloat16* Wtqkv = (__hip_bfloat16*)alloc((size_t)(3 * C_) * C_ * 2);
  __hip_bfloat16* Wt1a = (__hip_bfloat16*)alloc((size_t)FF_ * C_ * 2);
  __hip_bfloat16* Wt1b = (__hip_bfloat16*)alloc((size_t)FF_ * C_ * 2);
  __hip_bfloat16* Wt2a = (__hip_bfloat16*)alloc((size_t)C_ * FF_ * 2);
  __hip_bfloat16* Wt2b = (__hip_bfloat16*)alloc((size_t)C_ * FF_ * 2);
  // split-K partial for FFN2: reuse qkv region (dead after attn_mfma each
  // layer; 37.7 MB >= 25.2 MB needed; rewritten by next layer's QKV gemm).
  float* zpart = (float*)qkv;

  dim3 blk256(256);
  embed_kernel<<<M_, blk256, 0, stream>>>(x, embed, pos, h, hb);

  for (int l = 0; l < L_; ++l) {
    // all weight transposes for this layer up front (independent of h)
    transpose_cast<<<dim3(3 * C_ / 32, C_ / 32), dim3(32, 8), 0, stream>>>(
        Wqkv + (size_t)l * C_ * 3 * C_, Wtqkv, C_, 3 * C_);
    transpose_cast2<<<dim3(FF_ / 32, C_ / 32, 2), dim3(32, 8), 0, stream>>>(
        W1a + (size_t)l * C_ * FF_, Wt1a, W1b + (size_t)l * C_ * FF_, Wt1b,
        C_, FF_);
    transpose_cast2<<<dim3(C_ / 32, FF_ / 32, 2), dim3(32, 8), 0, stream>>>(
        W2a + (size_t)l * FF_ * C_, Wt2a, W2b + (size_t)l * FF_ * C_, Wt2b,
        FF_, C_);

    gemm_bt<0, 1><<<dim3(3 * C_ / 128, M_ / 128), blk256, 0, stream>>>(
        hb, Wtqkv, bqkv + (size_t)l * 3 * C_, qkv, nullptr, M_, 3 * C_, C_);
    attn_mfma<<<dim3(T_ / 128, B_ * H_), blk256, 0, stream>>>(qkv, ybuf);
    gemm_bt<1, 1><<<dim3(FF_ / 128, M_ / 128), blk256, 0, stream>>>(
        ybuf, Wt1a, b1a + (size_t)l * FF_, ubuf, nullptr, M_, FF_, C_);
    gemm_bt<0, 0><<<dim3(C_ / 128, M_ / 128, 2), blk256, 0, stream>>>(
        ubuf, Wt2a, b2a + (size_t)l * C_, zbuf, zpart, M_, C_, FF_);
    resid_ln2<<<M_, blk256, 0, stream>>>(h, zbuf, zpart, g1 + (size_t)l * C_,
                                         be1 + (size_t)l * C_, hb);
    gemm_bt<1, 1><<<dim3(FF_ / 128, M_ / 128), blk256, 0, stream>>>(
        hb, Wt1b, b1b + (size_t)l * FF_, ubuf, nullptr, M_, FF_, C_);
    gemm_bt<0, 0><<<dim3(C_ / 128, M_ / 128, 2), blk256, 0, stream>>>(
        ubuf, Wt2b, b2b + (size_t)l * C_, zbuf, zpart, M_, C_, FF_);
    resid_ln2<<<M_, blk256, 0, stream>>>(h, zbuf, zpart, g2 + (size_t)l * C_,
                                         be2 + (size_t)l * C_, hb);
  }

  transpose_cast<<<dim3(V_ / 32, C_ / 32), dim3(32, 8), 0, stream>>>(
      lmW, Wtqkv, C_, V_);
  gemm_bt<0, 0><<<dim3(V_ / 128, M_ / 128), blk256, 0, stream>>>(
      hb, Wtqkv, lmb, out, nullptr, M_, V_, C_);
}